// Round 11
// baseline (382.248 us; speedup 1.0000x reference)
//
#include <hip/hip_runtime.h>
#include <cstdint>

// B=4, S=2048, E=1024, H=4, DH=256, DQ=256
typedef _Float16 f16;
typedef unsigned short u16;
typedef __attribute__((ext_vector_type(8))) _Float16 half8;
typedef __attribute__((ext_vector_type(4))) _Float16 half4;
typedef __attribute__((ext_vector_type(2))) __fp16 fp16x2;
typedef __attribute__((ext_vector_type(4))) float f32x4;

#define MFMA_F16(a, b, c) __builtin_amdgcn_mfma_f32_16x16x32_f16(a, b, c, 0, 0, 0)

#define WAITVM8() asm volatile("s_waitcnt vmcnt(8)" ::: "memory")
#define WAITVM4() asm volatile("s_waitcnt vmcnt(4)" ::: "memory")
#define WAITVM2() asm volatile("s_waitcnt vmcnt(2)" ::: "memory")
#define WAITVM0() asm volatile("s_waitcnt vmcnt(0)" ::: "memory")
#define BARRIER() do { asm volatile("" ::: "memory"); __builtin_amdgcn_s_barrier(); \
                       asm volatile("" ::: "memory"); } while (0)

__device__ inline void stage16(const void* g, void* l) {
#if defined(__has_builtin) && __has_builtin(__builtin_amdgcn_global_load_lds)
  __builtin_amdgcn_global_load_lds(
      (const __attribute__((address_space(1))) unsigned*)g,
      (__attribute__((address_space(3))) unsigned*)l, 16, 0, 0);
#else
  *(int4*)l = *(const int4*)g;
#endif
}

__device__ inline int pack_f16(float a, float b) {
#if defined(__has_builtin) && __has_builtin(__builtin_amdgcn_cvt_pkrtz)
  union { fp16x2 h; int i; } u;
  u.h = __builtin_amdgcn_cvt_pkrtz(a, b);
  return u.i;
#else
  union { f16 h[2]; int i; } u;
  u.h[0] = (f16)a; u.h[1] = (f16)b;
  return u.i;
#endif
}

// ======================= fused fp32 -> fp16 conversion + weight layout =======================
__global__ __launch_bounds__(256)
void conv_all(const float* __restrict__ x, const float* __restrict__ wqkv,
              const float* __restrict__ w1, const float* __restrict__ wout,
              const float* __restrict__ w2, f16* __restrict__ dst) {
  int i = (blockIdx.x * 256 + threadIdx.x) * 8;
  const float* src; size_t dofs; float sc = 1.0f;
  if (i < 8388608)       { src = x + i;               dofs = i; }
  else if (i < 11534336) { src = wqkv + (i - 8388608); dofs = i; }
  else if (i < 12582912) { src = w1 + (i - 11534336);  dofs = i; }
  else if (i < 13631488) {
    int t = i - 12582912; int j = t >> 10, k = t & 1023;
    src = wout + t; dofs = 12582912 + (size_t)j * 2048 + k; sc = 1.8f;
  } else {
    int t = i - 13631488; int j = t >> 10, k = t & 1023;
    src = w2 + t; dofs = 12582912 + (size_t)j * 2048 + 1024 + k; sc = 0.2f;
  }
  float4 a = *(const float4*)src;
  float4 b = *(const float4*)(src + 4);
  half8 h;
  h[0] = (f16)(a.x * sc); h[1] = (f16)(a.y * sc); h[2] = (f16)(a.z * sc); h[3] = (f16)(a.w * sc);
  h[4] = (f16)(b.x * sc); h[5] = (f16)(b.y * sc); h[6] = (f16)(b.z * sc); h[7] = (f16)(b.w * sc);
  *(half8*)(dst + dofs) = h;
}

// ======================= filter table: ftab[k] = exp(i*1.5*atan(log(k+eps))) =======================
__global__ __launch_bounds__(256)
void filt_init(float2* __restrict__ ftab) {
  int k = blockIdx.x * 256 + threadIdx.x;
  if (k < 2048) {
    float s, c;
    sincosf(1.5f * atanf(logf((float)k + 1e-10f)), &s, &c);
    ftab[k] = make_float2(c, s);
  }
}

// ======================= fp16 MFMA GEMM, counted-vmcnt 2-phase, XCD-swizzled =======================
template<int EPI>
__global__ __launch_bounds__(256, 2)
void gemm_f16(const f16* __restrict__ A, const f16* __restrict__ W,
              const float* __restrict__ bias0, const float* __restrict__ bias1,
              void* __restrict__ out0, void* __restrict__ out1,
              f16* __restrict__ Vt, int N, int K) {
  __shared__ __align__(16) f16 lds[2][16384];
  const int tid = threadIdx.x;
  const int lane = tid & 63, w = tid >> 6;
  const int g = lane >> 4, lm = lane & 15;
  const int wr = w >> 1, wc = w & 1;
  const int nwg = gridDim.x * gridDim.y;
  const int flat = blockIdx.y * gridDim.x + blockIdx.x;
  const int logical = (flat & 7) * (nwg >> 3) + (flat >> 3);
  const int bx = logical % gridDim.x, by = logical / gridDim.x;
  const int m0 = by * 128, n0 = bx * 128;

  const f16* src[8];
#pragma unroll
  for (int j = 0; j < 8; ++j) {
    int u = j * 256 + tid;
    if (u < 1024) {
      int row = u >> 3, s = u & 7;
      src[j] = A + (size_t)(m0 + row) * K + ((s ^ (row & 7)) << 3);
    } else {
      int v = u - 1024;
      int row = v >> 3, s = v & 7;
      src[j] = W + (size_t)(n0 + row) * K + ((s ^ (row & 7)) << 3);
    }
  }

  f32x4 acc[4][4];
#pragma unroll
  for (int mt = 0; mt < 4; ++mt)
#pragma unroll
    for (int nt = 0; nt < 4; ++nt) acc[mt][nt] = (f32x4){0.f, 0.f, 0.f, 0.f};

#pragma unroll
  for (int j = 0; j < 8; ++j) stage16(src[j], &lds[0][(j * 256 + tid) * 8]);
  __syncthreads();

  const int KT = K >> 6;
#pragma unroll 1
  for (int t = 0; t < KT; ++t) {
    const f16* bufA = lds[t & 1];
    const f16* bufB = bufA + 8192;
    if (t + 1 < KT) {
#pragma unroll
      for (int j = 0; j < 8; ++j) {
        src[j] += 64;
        stage16(src[j], &lds[(t + 1) & 1][(j * 256 + tid) * 8]);
      }
      WAITVM8();
    } else {
      WAITVM0();
    }
    BARRIER();
#pragma unroll
    for (int ks = 0; ks < 2; ++ks) {
      half8 a[4], b[4];
#pragma unroll
      for (int mt = 0; mt < 4; ++mt) {
        int row = wr * 64 + mt * 16 + lm;
        a[mt] = *(const half8*)(bufA + row * 64 + (((ks * 4 + g) ^ (row & 7)) << 3));
      }
#pragma unroll
      for (int nt = 0; nt < 4; ++nt) {
        int row = wc * 64 + nt * 16 + lm;
        b[nt] = *(const half8*)(bufB + row * 64 + (((ks * 4 + g) ^ (row & 7)) << 3));
      }
#pragma unroll
      for (int mt = 0; mt < 4; ++mt)
#pragma unroll
        for (int nt = 0; nt < 4; ++nt)
          acc[mt][nt] = MFMA_F16(a[mt], b[nt], acc[mt][nt]);
    }
    BARRIER();
  }

  const int crow = m0 + wr * 64 + g * 4;
  const int ccol = n0 + wc * 64 + lm;
  if (EPI == 3) {
    if (n0 < 2048) {                       // Q,K region -> qkvF rows
      f16* qk = (f16*)out0;
#pragma unroll
      for (int nt = 0; nt < 4; ++nt) {
        float bb = bias0[ccol + nt * 16];
#pragma unroll
        for (int mt = 0; mt < 4; ++mt)
#pragma unroll
          for (int r = 0; r < 4; ++r)
            qk[(size_t)(crow + mt * 16 + r) * 3072 + ccol + nt * 16] =
                (f16)(acc[mt][nt][r] + bb);
      }
    } else if (n0 < 3072) {                // V region -> transposed Vt via LDS
      f16* ldsT = (f16*)lds;
#pragma unroll
      for (int nt = 0; nt < 4; ++nt) {
        float bb = bias0[ccol + nt * 16];
        int c = wc * 64 + nt * 16 + lm;
#pragma unroll
        for (int mt = 0; mt < 4; ++mt) {
          int r = wr * 64 + mt * 16 + g * 4;
#pragma unroll
          for (int rr = 0; rr < 4; ++rr)
            ldsT[c * 136 + r + rr] = (f16)(acc[mt][nt][rr] + bb);
        }
      }
      BARRIER();
      const int vbase0 = n0 - 2048;
      const int b = m0 >> 11, srow = m0 & 2047;
#pragma unroll
      for (int it = 0; it < 8; ++it) {
        int id = it * 256 + tid;
        int c = id >> 4, rb = id & 15;
        int vcol = vbase0 + c;
        int h = vcol >> 8, d = vcol & 255;
        half8 v = *(half8*)&ldsT[c * 136 + rb * 8];
        *(half8*)&Vt[(((size_t)(b * 4 + h)) * 256 + d) * 2048 + srow + rb * 8] = v;
      }
    } else {                               // h region -> GELU -> cat high half
      f16* cat = (f16*)out1;
      const int hc = ccol - 3072;
#pragma unroll
      for (int nt = 0; nt < 4; ++nt) {
        float bb = bias1[hc + nt * 16];
#pragma unroll
        for (int mt = 0; mt < 4; ++mt)
#pragma unroll
          for (int r = 0; r < 4; ++r) {
            float v = acc[mt][nt][r] + bb;
            v = 0.5f * v * (1.0f + erff(v * 0.70710678118654752f));
            cat[(size_t)(crow + mt * 16 + r) * 2048 + 1024 + hc + nt * 16] = (f16)v;
          }
      }
    }
  } else {                                 // EPI 4: chol f16
    f16* ch = (f16*)out0;
#pragma unroll
    for (int nt = 0; nt < 4; ++nt) {
      float bb = 1.8f * bias0[ccol + nt * 16] + 0.2f * bias1[ccol + nt * 16];
#pragma unroll
      for (int mt = 0; mt < 4; ++mt)
#pragma unroll
        for (int r = 0; r < 4; ++r)
          ch[(size_t)(crow + mt * 16 + r) * 1024 + ccol + nt * 16] =
              (f16)(acc[mt][nt][r] + bb);
    }
  }
}

// ======================= fp16 flash attention v7: split-KV (2 halves), 8 waves, grid 512 =======================
// Block = (bh, qt, kvh): 32 KV tiles of 32. Writes l-normalized partial O (f16) + (m,l) per q-row.
__global__ __launch_bounds__(512, 2)
void flash_f16(const f16* __restrict__ qkv, const f16* __restrict__ Vt,
               f16* __restrict__ Op, float2* __restrict__ ML) {
  __shared__ __align__(16) f16 lds[32768];   // K[2][32][256] @0, V[2][256][32] @16384
  const int tid = threadIdx.x;
  const int lane = tid & 63, w = tid >> 6;   // w 0..7
  const int g = lane >> 4, lm = lane & 15;
  const int raw = blockIdx.x;                // 512 blocks
  const int kvh = raw >> 8;
  const int bh = (raw & 7) * 2 + ((raw >> 7) & 1);  // XCD-clustered
  const int qt = (raw >> 3) & 15;
  const int b = bh >> 2, h = bh & 3;
  const int q0 = qt * 128 + w * 16;
  const float SC = 0.09016844005555896f;     // log2(e)/16

  half8 qf[8];
  {
    const f16* qp = qkv + (size_t)(b * 2048 + q0 + lm) * 3072 + h * 256 + g * 8;
#pragma unroll
    for (int c = 0; c < 8; ++c) qf[c] = *(const half8*)(qp + c * 32);
  }

  const f16* kbase = qkv + (size_t)b * 2048 * 3072 + 1024 + h * 256
                   + (size_t)kvh * 1024 * 3072;
  const f16* vbase = Vt + (size_t)bh * 256 * 2048 + kvh * 1024;
  int kofs[2], vofs[2];
#pragma unroll
  for (int j = 0; j < 2; ++j) {
    int u = j * 512 + tid;
    int kv = u >> 5, s = u & 31;
    kofs[j] = kv * 3072 + ((s ^ (kv & 7)) << 3);
    int d = u >> 2, sl = u & 3;
    vofs[j] = d * 2048 + ((sl ^ ((d >> 1) & 3)) << 3);
  }

  f32x4 o[16];
#pragma unroll
  for (int f = 0; f < 16; ++f) o[f] = (f32x4){0.f, 0.f, 0.f, 0.f};
  float m = -3e38f, l = 0.f;
  half8 paP = (half8){0, 0, 0, 0, 0, 0, 0, 0};

#pragma unroll
  for (int j = 0; j < 2; ++j) stage16(kbase + kofs[j], &lds[(j * 512 + tid) * 8]);

#pragma unroll 1
  for (int t = 0; t < 32; ++t) {
    const int cb_ = t & 1;
    if (t < 31) {
      const int kt = (t + 1) * 98304;
#pragma unroll
      for (int j = 0; j < 2; ++j)
        stage16(kbase + kofs[j] + kt, &lds[(cb_ ^ 1) * 8192 + (j * 512 + tid) * 8]);
    }
    {
      const int vt_ = t * 32;
#pragma unroll
      for (int j = 0; j < 2; ++j)
        stage16(vbase + vofs[j] + vt_, &lds[16384 + cb_ * 8192 + (j * 512 + tid) * 8]);
    }
    if (t < 31) { WAITVM4(); } else { WAITVM2(); }
    BARRIER();

    const f16* kb = &lds[cb_ * 8192];

    // ---- QK(t): S^T[kv][q] = mfma(A=K, B=Q) ----
    f32x4 s0 = {0.f, 0.f, 0.f, 0.f}, s1 = {0.f, 0.f, 0.f, 0.f};
    __builtin_amdgcn_s_setprio(1);
#pragma unroll
    for (int c = 0; c < 8; ++c) {
      int slot = ((c * 4 + g) ^ (lm & 7)) << 3;
      half8 b0 = *(const half8*)(kb + lm * 256 + slot);
      half8 b1 = *(const half8*)(kb + (16 + lm) * 256 + slot);
      s0 = MFMA_F16(b0, qf[c], s0);
      s1 = MFMA_F16(b1, qf[c], s1);
    }
    __builtin_amdgcn_s_setprio(0);

    // ---- PV(t-1) ----
    if (t > 0) {
      const f16* vbp = &lds[16384 + (cb_ ^ 1) * 8192];
      __builtin_amdgcn_s_setprio(1);
#pragma unroll
      for (int f = 0; f < 16; ++f) {
        int d = f * 16 + lm;
        half8 bv = *(const half8*)(vbp + d * 32 + ((g ^ ((d >> 1) & 3)) << 3));
        o[f] = MFMA_F16(paP, bv, o[f]);
      }
      __builtin_amdgcn_s_setprio(0);
    }

    // ---- softmax(t), defer-max (log2 domain) ----
    float a0[4], a1[4];
#pragma unroll
    for (int r = 0; r < 4; ++r) { a0[r] = s0[r] * SC; a1[r] = s1[r] * SC; }
    float mx = fmaxf(fmaxf(fmaxf(a0[0], a0[1]), fmaxf(a0[2], a0[3])),
                     fmaxf(fmaxf(a1[0], a1[1]), fmaxf(a1[2], a1[3])));
    mx = fmaxf(mx, __shfl_xor(mx, 16));
    mx = fmaxf(mx, __shfl_xor(mx, 32));

    if (!__all(mx <= m + 8.0f)) {
      float mn = fmaxf(m, mx);
      float corr = exp2f(m - mn);
      m = mn; l *= corr;
#pragma unroll
      for (int r = 0; r < 4; ++r) {
        float cr = __shfl(corr, ((lane >> 2) & 12) + r);
#pragma unroll
        for (int f = 0; f < 16; ++f) o[f][r] *= cr;
      }
    }

    float e0[4], e1[4], rs;
#pragma unroll
    for (int r = 0; r < 4; ++r) { e0[r] = exp2f(a0[r] - m); e1[r] = exp2f(a1[r] - m); }
    rs = ((e0[0] + e0[1]) + (e0[2] + e0[3])) + ((e1[0] + e1[1]) + (e1[2] + e1[3]));
    rs += __shfl_xor(rs, 16);
    rs += __shfl_xor(rs, 32);
    l += rs;

    int A01 = pack_f16(e0[0], e0[1]);
    int A23 = pack_f16(e0[2], e0[3]);
    int B01 = pack_f16(e1[0], e1[1]);
    int B23 = pack_f16(e1[2], e1[3]);
    const int s1l = ((lane & 16) << 1) + lm;
    const int s2l = s1l + 16;
    int t0a = __shfl(A01, s1l), t0b = __shfl(B01, s1l);
    int t1a = __shfl(A23, s1l), t1b = __shfl(B23, s1l);
    int t2a = __shfl(A01, s2l), t2b = __shfl(B01, s2l);
    int t3a = __shfl(A23, s2l), t3b = __shfl(B23, s2l);
    union { int i[4]; half8 h; } pau;
    const bool hi = lane >= 32;
    pau.i[0] = hi ? t0b : t0a;
    pau.i[1] = hi ? t1b : t1a;
    pau.i[2] = hi ? t2b : t2a;
    pau.i[3] = hi ? t3b : t3a;
    paP = pau.h;

    BARRIER();
  }

  // ---- epilogue: PV(31) ----
  WAITVM0();
  BARRIER();
  {
    const f16* vbp = &lds[16384 + 8192];   // vbuf[31 & 1 = 1]
#pragma unroll
    for (int f = 0; f < 16; ++f) {
      int d = f * 16 + lm;
      half8 bv = *(const half8*)(vbp + d * 32 + ((g ^ ((d >> 1) & 3)) << 3));
      o[f] = MFMA_F16(paP, bv, o[f]);
    }
  }

  // write (m,l) per q-row (rows q0..q0+15, value lives at lane lm per row)
  const size_t seg = (size_t)(kvh * 16 + bh) * 2048;
  if (lane < 16) ML[seg + q0 + lm] = make_float2(m, l);

  // write l-normalized partial O (f16), bounded by |V|max
  float inv[4];
#pragma unroll
  for (int r = 0; r < 4; ++r) inv[r] = 1.0f / __shfl(l, ((lane >> 2) & 12) + r);
  f16* op = Op + (seg + q0) * 256;
#pragma unroll
  for (int f = 0; f < 16; ++f)
#pragma unroll
    for (int r = 0; r < 4; ++r)
      op[(size_t)(g * 4 + r) * 256 + f * 16 + lm] = (f16)(o[f][r] * inv[r]);
}

// ======================= combine: merge the two KV halves =======================
__global__ __launch_bounds__(256)
void combine(const f16* __restrict__ Op, const float2* __restrict__ ML,
             f16* __restrict__ cat) {
  int id = blockIdx.x * 256 + threadIdx.x;   // 1,048,576
  int rrow = id >> 5;                        // bh*2048 + q
  int dseg = (id & 31) * 8;
  int bh = rrow >> 11, q = rrow & 2047;
  int b = bh >> 2, h = bh & 3;
  float2 ml1 = ML[rrow];
  float2 ml2 = ML[32768 + rrow];
  float M = fmaxf(ml1.x, ml2.x);
  float w1 = ml1.y * exp2f(ml1.x - M);
  float w2 = ml2.y * exp2f(ml2.x - M);
  float inv = 1.0f / (w1 + w2);
  w1 *= inv; w2 *= inv;
  half8 o1 = *(const half8*)(Op + (size_t)rrow * 256 + dseg);
  half8 o2 = *(const half8*)(Op + (size_t)(32768 + rrow) * 256 + dseg);
  half8 out;
#pragma unroll
  for (int j = 0; j < 8; ++j)
    out[j] = (f16)((float)o1[j] * w1 + (float)o2[j] * w2);
  *(half8*)(cat + ((size_t)(b * 2048 + q)) * 2048 + h * 256 + dseg) = out;
}

// ======================= Spectral v5 (f16 input, filter table) =======================
__device__ inline float2 cmul(float2 a, float2 b) {
  return make_float2(a.x * b.x - a.y * b.y, a.x * b.y + a.y * b.x);
}
__device__ inline float2 cmulc(float2 a, float2 b) {
  return make_float2(a.x * b.x + a.y * b.y, a.y * b.x - a.x * b.y);
}
__device__ inline void qcube(float2& w, float2& x, float2& y, float2& z, float2 f) {
  w = cmul(w, f); x = cmul(x, f); y = cmul(y, f); z = cmul(z, f);
  float2 a2 = cmul(w, w);
  float2 sx = cmul(x, x), sy = cmul(y, y), sz = cmul(z, z);
  float2 s = make_float2(sx.x + sy.x + sz.x, sx.y + sy.y + sz.y);
  float2 t3 = make_float2(a2.x - 3.f * s.x, a2.y - 3.f * s.y);
  float2 cf = make_float2(3.f * a2.x - s.x, 3.f * a2.y - s.y);
  w = cmul(w, t3); x = cmul(cf, x); y = cmul(cf, y); z = cmul(cf, z);
}

__device__ inline int fftpos(int k) {
  int kp = k >> 1;
  return ((k & 1) << 10) | ((kp & 3) << 8) | ((kp & 12) << 4) | (kp & 48)
       | ((kp >> 4) & 12) | ((kp >> 8) & 3);
}

__global__ __launch_bounds__(256)
void spectral5(const f16* __restrict__ chol, const float* __restrict__ xin,
               const float2* __restrict__ ftab, float* __restrict__ outp) {
  __shared__ __align__(16) float2 Z[2][2048];
  __shared__ float2 tw[1024];
  const int tid = threadIdx.x;
  const int b = blockIdx.x >> 8;
  const int qd = blockIdx.x & 255;
  const size_t c0 = (size_t)qd * 4;
  const f16* cb = chol + (size_t)b * 2048 * 1024;

  for (int j = tid; j < 1024; j += 256) {
    float ang = -6.2831853071795864769f * (float)j * (1.0f / 2048.0f);
    float sv, cv; sincosf(ang, &sv, &cv);
    tw[j] = make_float2(cv, sv);
  }
  for (int s = tid; s < 2048; s += 256) {
    half4 v = *(const half4*)(cb + (size_t)s * 1024 + c0);
    Z[0][s] = make_float2((float)v[0], (float)v[1]);
    Z[1][s] = make_float2((float)v[2], (float)v[3]);
  }
  __syncthreads();

#pragma unroll 1
  for (int it = 0; it < 8; ++it) {
    int gg = it * 256 + tid;
    int c = gg >> 10, j = gg & 1023;
    float2 a = Z[c][j], bb = Z[c][j + 1024];
    Z[c][j] = make_float2(a.x + bb.x, a.y + bb.y);
    Z[c][j + 1024] = cmul(make_float2(a.x - bb.x, a.y - bb.y), tw[j]);
  }
  __syncthreads();

#pragma unroll 1
  for (int lq = 8; lq >= 0; lq -= 2) {
    const int Q = 1 << lq, st = 512 >> lq;
#pragma unroll 1
    for (int it = 0; it < 4; ++it) {
      int gg = it * 256 + tid;
      int c = gg >> 9, bf = gg & 511;
      int j = bf & (Q - 1);
      int base = ((bf >> lq) << (lq + 2)) | j;
      float2 a = Z[c][base], bq = Z[c][base + Q];
      float2 cc = Z[c][base + 2 * Q], d = Z[c][base + 3 * Q];
      float2 t0 = make_float2(a.x + cc.x, a.y + cc.y);
      float2 t1 = make_float2(a.x - cc.x, a.y - cc.y);
      float2 t2 = make_float2(bq.x + d.x, bq.y + d.y);
      float2 bd = make_float2(bq.x - d.x, bq.y - d.y);
      float2 t3 = make_float2(bd.y, -bd.x);
      float2 y0 = make_float2(t0.x + t2.x, t0.y + t2.y);
      float2 y1 = make_float2(t1.x + t3.x, t1.y + t3.y);
      float2 y2 = make_float2(t0.x - t2.x, t0.y - t2.y);
      float2 y3 = make_float2(t1.x - t3.x, t1.y - t3.y);
      int i3 = 3 * j * st;
      float sg = (i3 & 1024) ? -1.f : 1.f;
      i3 &= 1023;
      Z[c][base] = y0;
      Z[c][base + Q] = cmul(y1, tw[j * st]);
      Z[c][base + 2 * Q] = cmul(y2, tw[2 * j * st]);
      float2 r3 = cmul(y3, tw[i3]);
      Z[c][base + 3 * Q] = make_float2(r3.x * sg, r3.y * sg);
    }
    __syncthreads();
  }

#pragma unroll 1
  for (int it = 0; it < 4; ++it) {
    int jj = it * 256 + tid;
    int nrep = (jj == 0) ? 2 : 1;
#pragma unroll 1
    for (int rep = 0; rep < nrep; ++rep) {
      int k  = (jj == 0) ? (rep ? 1024 : 0) : jj;
      int kn = (jj == 0) ? k : 2048 - jj;
      int p  = fftpos(k);
      int pp = fftpos(kn);
      float2 z0p = Z[0][p], z0q = Z[0][pp];
      float2 z1p = Z[1][p], z1q = Z[1][pp];
      float2 wk = make_float2(0.5f * (z0p.x + z0q.x), 0.5f * (z0p.y - z0q.y));
      float2 xk = make_float2(0.5f * (z0p.y + z0q.y), 0.5f * (z0q.x - z0p.x));
      float2 yk = make_float2(0.5f * (z1p.x + z1q.x), 0.5f * (z1p.y - z1q.y));
      float2 zk = make_float2(0.5f * (z1p.y + z1q.y), 0.5f * (z1q.x - z1p.x));
      float2 wn = make_float2(0.5f * (z0q.x + z0p.x), 0.5f * (z0q.y - z0p.y));
      float2 xn = make_float2(0.5f * (z0q.y + z0p.y), 0.5f * (z0p.x - z0q.x));
      float2 yn = make_float2(0.5f * (z1q.x + z1p.x), 0.5f * (z1q.y - z1p.y));
      float2 zn = make_float2(0.5f * (z1q.y + z1p.y), 0.5f * (z1p.x - z1q.x));
      float2 fk = ftab[k], fn = ftab[kn];
      qcube(wk, xk, yk, zk, fk);
      qcube(wn, xn, yn, zn, fn);
      Z[0][p]  = make_float2(0.5f * (wk.x + wn.x) - 0.5f * (xk.y - xn.y),
                             0.5f * (wk.y - wn.y) + 0.5f * (xk.x + xn.x));
      Z[0][pp] = make_float2(0.5f * (wn.x + wk.x) - 0.5f * (xn.y - xk.y),
                             0.5f * (wn.y - wk.y) + 0.5f * (xn.x + xk.x));
      Z[1][p]  = make_float2(0.5f * (yk.x + yn.x) - 0.5f * (zk.y - zn.y),
                             0.5f * (yk.y - yn.y) + 0.5f * (zk.x + zn.x));
      Z[1][pp] = make_float2(0.5f * (yn.x + yk.x) - 0.5f * (zn.y - zk.y),
                             0.5f * (yn.y - yk.y) + 0.5f * (zn.x + zk.x));
    }
  }
  __syncthreads();

#pragma unroll 1
  for (int lq = 0; lq <= 8; lq += 2) {
    const int Q = 1 << lq, st = 512 >> lq;
#pragma unroll 1
    for (int it = 0; it < 4; ++it) {
      int gg = it * 256 + tid;
      int c = gg >> 9, bf = gg & 511;
      int j = bf & (Q - 1);
      int base = ((bf >> lq) << (lq + 2)) | j;
      float2 a = Z[c][base];
      float2 bq = cmulc(Z[c][base + Q], tw[j * st]);
      float2 cc = cmulc(Z[c][base + 2 * Q], tw[2 * j * st]);
      int i3 = 3 * j * st;
      float sg = (i3 & 1024) ? -1.f : 1.f;
      i3 &= 1023;
      float2 d = cmulc(Z[c][base + 3 * Q], tw[i3]);
      d = make_float2(d.x * sg, d.y * sg);
      float2 t0 = make_float2(a.x + cc.x, a.y + cc.y);
      float2 t1 = make_float2(a.x - cc.x, a.y - cc.y);
      float2 t2 = make_float2(bq.x + d.x, bq.y + d.y);
      float2 bd = make_float2(bq.x - d.x, bq.y - d.y);
      float2 t3 = make_float2(-bd.y, bd.x);
      Z[c][base]         = make_float2(t0.x + t2.x, t0.y + t2.y);
      Z[c][base + Q]     = make_float2(t1.x + t3.x, t1.y + t3.y);
      Z[c][base + 2 * Q] = make_float2(t0.x - t2.x, t0.y - t2.y);
      Z[c][base + 3 * Q] = make_float2(t1.x - t3.x, t1.y - t3.y);
    }
    __syncthreads();
  }

#pragma unroll 1
  for (int it = 0; it < 8; ++it) {
    int gg = it * 256 + tid;
    int c = gg >> 10, j = gg & 1023;
    float2 a = Z[c][j];
    float2 bw = cmulc(Z[c][j + 1024], tw[j]);
    Z[c][j] = make_float2(a.x + bw.x, a.y + bw.y);
    Z[c][j + 1024] = make_float2(a.x - bw.x, a.y - bw.y);
  }
  __syncthreads();

  const float* xb = xin + (size_t)b * 2048 * 1024;
  float* ob = outp + (size_t)b * 2048 * 1024;
  const float inv = 1.0f / 2048.0f;
  for (int s = tid; s < 2048; s += 256) {
    float4 xv = *(const float4*)(xb + (size_t)s * 1024 + c0);
    float2 r0 = Z[0][s], r1 = Z[1][s];
    float4 o;
    o.x = xv.x * r0.x * inv;
    o.y = xv.y * r0.y * inv;
    o.z = xv.z * r1.x * inv;
    o.w = xv.w * r1.y * inv;
    *(float4*)(ob + (size_t)s * 1024 + c0) = o;
  }
}

// ======================= launch =======================
extern "C" void kernel_launch(void* const* d_in, const int* in_sizes, int n_in,
                              void* d_out, int out_size, void* d_ws, size_t ws_size,
                              hipStream_t stream) {
  const float* x    = (const float*)d_in[0];
  const float* wqkv = (const float*)d_in[1];
  const float* bqkv = (const float*)d_in[2];
  const float* wout = (const float*)d_in[3];
  const float* bout = (const float*)d_in[4];
  const float* w1   = (const float*)d_in[5];
  const float* b1   = (const float*)d_in[6];
  const float* w2   = (const float*)d_in[7];
  const float* b2   = (const float*)d_in[8];
  float* out = (float*)d_out;
  char* wsb = (char*)d_ws;
  const size_t MB = 1048576;

  // ws: xf 16@0 | wqf 8@16 | wcat 8@24 | qkvF 48@32 | VtF 16@80 | cat 32@96
  //   | chol 16@128 | Op f16 34@144 | ML 0.5@178 | ftab @179
  f16*   xf    = (f16*)(wsb);
  f16*   wqf   = (f16*)(wsb + 16 * MB);
  f16*   wcat  = (f16*)(wsb + 24 * MB);
  f16*   qkvF  = (f16*)(wsb + 32 * MB);
  f16*   VtF   = (f16*)(wsb + 80 * MB);
  f16*   cat   = (f16*)(wsb + 96 * MB);
  f16*   chol  = (f16*)(wsb + 128 * MB);
  f16*   Op    = (f16*)(wsb + 144 * MB);
  float2* ML   = (float2*)(wsb + 178 * MB);
  float2* ftab = (float2*)(wsb + 179 * MB);

  filt_init<<<8, 256, 0, stream>>>(ftab);
  conv_all<<<7168, 256, 0, stream>>>(x, wqkv, w1, wout, w2, xf);

  // GEMM A: [qkv | gelu(h)] = xf @ [Wqkv;W1]^T; V written transposed to VtF
  gemm_f16<3><<<dim3(32, 64), 256, 0, stream>>>(xf, wqf, bqkv, b1, qkvF, cat, VtF, 4096, 1024);
  // flash split-KV: 512 blocks, partial O + (m,l)
  flash_f16<<<512, 512, 0, stream>>>(qkvF, VtF, Op, ML);
  combine<<<4096, 256, 0, stream>>>(Op, ML, cat);
  // GEMM B: chol2 = [attn|h] @ [1.8Wout|0.2W2]^T + 1.8bout + 0.2b2
  gemm_f16<4><<<dim3(8, 64), 256, 0, stream>>>(cat, wcat, bout, b2, chol, nullptr, nullptr, 1024, 2048);
  spectral5<<<1024, 256, 0, stream>>>(chol, x, ftab, out);
}

// Round 12
// 352.687 us; speedup vs baseline: 1.0838x; 1.0838x over previous
//
#include <hip/hip_runtime.h>
#include <cstdint>

// B=4, S=2048, E=1024, H=4, DH=256, DQ=256
typedef _Float16 f16;
typedef unsigned short u16;
typedef __attribute__((ext_vector_type(8))) _Float16 half8;
typedef __attribute__((ext_vector_type(4))) _Float16 half4;
typedef __attribute__((ext_vector_type(2))) __fp16 fp16x2;
typedef __attribute__((ext_vector_type(4))) float f32x4;

#define MFMA_F16(a, b, c) __builtin_amdgcn_mfma_f32_16x16x32_f16(a, b, c, 0, 0, 0)

#define WAITVM8() asm volatile("s_waitcnt vmcnt(8)" ::: "memory")
#define WAITVM4() asm volatile("s_waitcnt vmcnt(4)" ::: "memory")
#define WAITVM2() asm volatile("s_waitcnt vmcnt(2)" ::: "memory")
#define WAITVM0() asm volatile("s_waitcnt vmcnt(0)" ::: "memory")
#define BARRIER() do { asm volatile("" ::: "memory"); __builtin_amdgcn_s_barrier(); \
                       asm volatile("" ::: "memory"); } while (0)

__device__ inline void stage16(const void* g, void* l) {
#if defined(__has_builtin) && __has_builtin(__builtin_amdgcn_global_load_lds)
  __builtin_amdgcn_global_load_lds(
      (const __attribute__((address_space(1))) unsigned*)g,
      (__attribute__((address_space(3))) unsigned*)l, 16, 0, 0);
#else
  *(int4*)l = *(const int4*)g;
#endif
}

__device__ inline int pack_f16(float a, float b) {
#if defined(__has_builtin) && __has_builtin(__builtin_amdgcn_cvt_pkrtz)
  union { fp16x2 h; int i; } u;
  u.h = __builtin_amdgcn_cvt_pkrtz(a, b);
  return u.i;
#else
  union { f16 h[2]; int i; } u;
  u.h[0] = (f16)a; u.h[1] = (f16)b;
  return u.i;
#endif
}

// ======================= fused fp32 -> fp16 conversion + weight layout =======================
__global__ __launch_bounds__(256)
void conv_all(const float* __restrict__ x, const float* __restrict__ wqkv,
              const float* __restrict__ w1, const float* __restrict__ wout,
              const float* __restrict__ w2, f16* __restrict__ dst) {
  int i = (blockIdx.x * 256 + threadIdx.x) * 8;
  const float* src; size_t dofs; float sc = 1.0f;
  if (i < 8388608)       { src = x + i;               dofs = i; }
  else if (i < 11534336) { src = wqkv + (i - 8388608); dofs = i; }
  else if (i < 12582912) { src = w1 + (i - 11534336);  dofs = i; }
  else if (i < 13631488) {
    int t = i - 12582912; int j = t >> 10, k = t & 1023;
    src = wout + t; dofs = 12582912 + (size_t)j * 2048 + k; sc = 1.8f;
  } else {
    int t = i - 13631488; int j = t >> 10, k = t & 1023;
    src = w2 + t; dofs = 12582912 + (size_t)j * 2048 + 1024 + k; sc = 0.2f;
  }
  float4 a = *(const float4*)src;
  float4 b = *(const float4*)(src + 4);
  half8 h;
  h[0] = (f16)(a.x * sc); h[1] = (f16)(a.y * sc); h[2] = (f16)(a.z * sc); h[3] = (f16)(a.w * sc);
  h[4] = (f16)(b.x * sc); h[5] = (f16)(b.y * sc); h[6] = (f16)(b.z * sc); h[7] = (f16)(b.w * sc);
  *(half8*)(dst + dofs) = h;
}

// ======================= filter table: ftab[k] = exp(i*1.5*atan(log(k+eps))) =======================
__global__ __launch_bounds__(256)
void filt_init(float2* __restrict__ ftab) {
  int k = blockIdx.x * 256 + threadIdx.x;
  if (k < 2048) {
    float s, c;
    sincosf(1.5f * atanf(logf((float)k + 1e-10f)), &s, &c);
    ftab[k] = make_float2(c, s);
  }
}

// ======================= fp16 MFMA GEMM, counted-vmcnt 2-phase, XCD-swizzled =======================
// EPI=3: A=xf, W=[Wqkv;W1] N=4096:
//   n0<2048  -> +bqkv -> qkvF (f16, stride 3072)
//   n0<3072  -> +bqkv -> transposed via LDS -> Vt
//   n0>=3072 -> +b1, GELU -> cat[row][1024+c'] (stride 2048)
// EPI=4: A=cat(K=2048), W=Wcat: cholT[1024][8192] f16 = (acc + 1.8*bout + 0.2*b2)^T via LDS
template<int EPI>
__global__ __launch_bounds__(256, 2)
void gemm_f16(const f16* __restrict__ A, const f16* __restrict__ W,
              const float* __restrict__ bias0, const float* __restrict__ bias1,
              void* __restrict__ out0, void* __restrict__ out1,
              f16* __restrict__ Vt, int N, int K) {
  __shared__ __align__(16) f16 lds[2][16384];
  const int tid = threadIdx.x;
  const int lane = tid & 63, w = tid >> 6;
  const int g = lane >> 4, lm = lane & 15;
  const int wr = w >> 1, wc = w & 1;
  const int nwg = gridDim.x * gridDim.y;
  const int flat = blockIdx.y * gridDim.x + blockIdx.x;
  const int logical = (flat & 7) * (nwg >> 3) + (flat >> 3);
  const int bx = logical % gridDim.x, by = logical / gridDim.x;
  const int m0 = by * 128, n0 = bx * 128;

  const f16* src[8];
#pragma unroll
  for (int j = 0; j < 8; ++j) {
    int u = j * 256 + tid;
    if (u < 1024) {
      int row = u >> 3, s = u & 7;
      src[j] = A + (size_t)(m0 + row) * K + ((s ^ (row & 7)) << 3);
    } else {
      int v = u - 1024;
      int row = v >> 3, s = v & 7;
      src[j] = W + (size_t)(n0 + row) * K + ((s ^ (row & 7)) << 3);
    }
  }

  f32x4 acc[4][4];
#pragma unroll
  for (int mt = 0; mt < 4; ++mt)
#pragma unroll
    for (int nt = 0; nt < 4; ++nt) acc[mt][nt] = (f32x4){0.f, 0.f, 0.f, 0.f};

#pragma unroll
  for (int j = 0; j < 8; ++j) stage16(src[j], &lds[0][(j * 256 + tid) * 8]);
  __syncthreads();

  const int KT = K >> 6;
#pragma unroll 1
  for (int t = 0; t < KT; ++t) {
    const f16* bufA = lds[t & 1];
    const f16* bufB = bufA + 8192;
    if (t + 1 < KT) {
#pragma unroll
      for (int j = 0; j < 8; ++j) {
        src[j] += 64;
        stage16(src[j], &lds[(t + 1) & 1][(j * 256 + tid) * 8]);
      }
      WAITVM8();
    } else {
      WAITVM0();
    }
    BARRIER();
#pragma unroll
    for (int ks = 0; ks < 2; ++ks) {
      half8 a[4], b[4];
#pragma unroll
      for (int mt = 0; mt < 4; ++mt) {
        int row = wr * 64 + mt * 16 + lm;
        a[mt] = *(const half8*)(bufA + row * 64 + (((ks * 4 + g) ^ (row & 7)) << 3));
      }
#pragma unroll
      for (int nt = 0; nt < 4; ++nt) {
        int row = wc * 64 + nt * 16 + lm;
        b[nt] = *(const half8*)(bufB + row * 64 + (((ks * 4 + g) ^ (row & 7)) << 3));
      }
#pragma unroll
      for (int mt = 0; mt < 4; ++mt)
#pragma unroll
        for (int nt = 0; nt < 4; ++nt)
          acc[mt][nt] = MFMA_F16(a[mt], b[nt], acc[mt][nt]);
    }
    BARRIER();
  }

  const int crow = m0 + wr * 64 + g * 4;
  const int ccol = n0 + wc * 64 + lm;
  if (EPI == 3) {
    if (n0 < 2048) {                       // Q,K region -> qkvF rows
      f16* qk = (f16*)out0;
#pragma unroll
      for (int nt = 0; nt < 4; ++nt) {
        float bb = bias0[ccol + nt * 16];
#pragma unroll
        for (int mt = 0; mt < 4; ++mt)
#pragma unroll
          for (int r = 0; r < 4; ++r)
            qk[(size_t)(crow + mt * 16 + r) * 3072 + ccol + nt * 16] =
                (f16)(acc[mt][nt][r] + bb);
      }
    } else if (n0 < 3072) {                // V region -> transposed Vt via LDS
      f16* ldsT = (f16*)lds;
#pragma unroll
      for (int nt = 0; nt < 4; ++nt) {
        float bb = bias0[ccol + nt * 16];
        int c = wc * 64 + nt * 16 + lm;
#pragma unroll
        for (int mt = 0; mt < 4; ++mt) {
          int r = wr * 64 + mt * 16 + g * 4;
#pragma unroll
          for (int rr = 0; rr < 4; ++rr)
            ldsT[c * 136 + r + rr] = (f16)(acc[mt][nt][rr] + bb);
        }
      }
      BARRIER();
      const int vbase0 = n0 - 2048;
      const int b = m0 >> 11, srow = m0 & 2047;
#pragma unroll
      for (int it = 0; it < 8; ++it) {
        int id = it * 256 + tid;
        int c = id >> 4, rb = id & 15;
        int vcol = vbase0 + c;
        int h = vcol >> 8, d = vcol & 255;
        half8 v = *(half8*)&ldsT[c * 136 + rb * 8];
        *(half8*)&Vt[(((size_t)(b * 4 + h)) * 256 + d) * 2048 + srow + rb * 8] = v;
      }
    } else {                               // h region -> GELU -> cat high half
      f16* cat = (f16*)out1;
      const int hc = ccol - 3072;
#pragma unroll
      for (int nt = 0; nt < 4; ++nt) {
        float bb = bias1[hc + nt * 16];
#pragma unroll
        for (int mt = 0; mt < 4; ++mt)
#pragma unroll
          for (int r = 0; r < 4; ++r) {
            float v = acc[mt][nt][r] + bb;
            v = 0.5f * v * (1.0f + erff(v * 0.70710678118654752f));
            cat[(size_t)(crow + mt * 16 + r) * 2048 + 1024 + hc + nt * 16] = (f16)v;
          }
      }
    }
  } else {                                 // EPI 4: cholT (transposed) via LDS
    f16* ldsT = (f16*)lds;                 // [128 c][136 r]
#pragma unroll
    for (int nt = 0; nt < 4; ++nt) {
      float bb = 1.8f * bias0[ccol + nt * 16] + 0.2f * bias1[ccol + nt * 16];
      int c = wc * 64 + nt * 16 + lm;
#pragma unroll
      for (int mt = 0; mt < 4; ++mt) {
        int r = wr * 64 + mt * 16 + g * 4;
#pragma unroll
        for (int rr = 0; rr < 4; ++rr)
          ldsT[c * 136 + r + rr] = (f16)(acc[mt][nt][rr] + bb);
      }
    }
    BARRIER();
    f16* ch = (f16*)out0;                  // cholT [1024 ch][8192 rows]
#pragma unroll
    for (int it = 0; it < 8; ++it) {
      int id = it * 256 + tid;
      int c = id >> 4, rb = id & 15;
      half8 v = *(half8*)&ldsT[c * 136 + rb * 8];
      *(half8*)&ch[(size_t)(n0 + c) * 8192 + m0 + rb * 8] = v;
    }
  }
}

// ======================= fp16 flash attention v6 (r10, proven): 8 waves / BQ=128, grid 256 =======================
__global__ __launch_bounds__(512, 2)
void flash_f16(const f16* __restrict__ qkv, const f16* __restrict__ Vt,
               f16* __restrict__ attn) {
  __shared__ __align__(16) f16 lds[32768];   // K[2][32][256] @0, V[2][256][32] @16384
  const int tid = threadIdx.x;
  const int lane = tid & 63, w = tid >> 6;   // w 0..7
  const int g = lane >> 4, lm = lane & 15;
  const int raw = blockIdx.x;                // 256 blocks
  const int bh = (raw & 7) * 2 + (raw >> 7); // XCD x -> bh {2x, 2x+1}
  const int qt = (raw >> 3) & 15;
  const int b = bh >> 2, h = bh & 3;
  const int q0 = qt * 128 + w * 16;
  const float SC = 0.09016844005555896f;     // log2(e)/16

  half8 qf[8];
  {
    const f16* qp = qkv + (size_t)(b * 2048 + q0 + lm) * 3072 + h * 256 + g * 8;
#pragma unroll
    for (int c = 0; c < 8; ++c) qf[c] = *(const half8*)(qp + c * 32);
  }

  const f16* kbase = qkv + (size_t)b * 2048 * 3072 + 1024 + h * 256;
  const f16* vbase = Vt + (size_t)bh * 256 * 2048;
  int kofs[2], vofs[2];
#pragma unroll
  for (int j = 0; j < 2; ++j) {
    int u = j * 512 + tid;
    int kv = u >> 5, s = u & 31;
    kofs[j] = kv * 3072 + ((s ^ (kv & 7)) << 3);
    int d = u >> 2, sl = u & 3;
    vofs[j] = d * 2048 + ((sl ^ ((d >> 1) & 3)) << 3);
  }

  f32x4 o[16];
#pragma unroll
  for (int f = 0; f < 16; ++f) o[f] = (f32x4){0.f, 0.f, 0.f, 0.f};
  float m = -3e38f, l = 0.f;
  half8 paP = (half8){0, 0, 0, 0, 0, 0, 0, 0};

#pragma unroll
  for (int j = 0; j < 2; ++j) stage16(kbase + kofs[j], &lds[(j * 512 + tid) * 8]);

#pragma unroll 1
  for (int t = 0; t < 64; ++t) {
    const int cb_ = t & 1;
    if (t < 63) {
      const int kt = (t + 1) * 98304;
#pragma unroll
      for (int j = 0; j < 2; ++j)
        stage16(kbase + kofs[j] + kt, &lds[(cb_ ^ 1) * 8192 + (j * 512 + tid) * 8]);
    }
    {
      const int vt_ = t * 32;
#pragma unroll
      for (int j = 0; j < 2; ++j)
        stage16(vbase + vofs[j] + vt_, &lds[16384 + cb_ * 8192 + (j * 512 + tid) * 8]);
    }
    if (t < 63) { WAITVM4(); } else { WAITVM2(); }
    BARRIER();

    const f16* kb = &lds[cb_ * 8192];

    // ---- QK(t): S^T[kv][q] = mfma(A=K, B=Q) ----
    f32x4 s0 = {0.f, 0.f, 0.f, 0.f}, s1 = {0.f, 0.f, 0.f, 0.f};
    __builtin_amdgcn_s_setprio(1);
#pragma unroll
    for (int c = 0; c < 8; ++c) {
      int slot = ((c * 4 + g) ^ (lm & 7)) << 3;
      half8 b0 = *(const half8*)(kb + lm * 256 + slot);
      half8 b1 = *(const half8*)(kb + (16 + lm) * 256 + slot);
      s0 = MFMA_F16(b0, qf[c], s0);
      s1 = MFMA_F16(b1, qf[c], s1);
    }
    __builtin_amdgcn_s_setprio(0);

    // ---- PV(t-1) ----
    if (t > 0) {
      const f16* vbp = &lds[16384 + (cb_ ^ 1) * 8192];
      __builtin_amdgcn_s_setprio(1);
#pragma unroll
      for (int f = 0; f < 16; ++f) {
        int d = f * 16 + lm;
        half8 bv = *(const half8*)(vbp + d * 32 + ((g ^ ((d >> 1) & 3)) << 3));
        o[f] = MFMA_F16(paP, bv, o[f]);
      }
      __builtin_amdgcn_s_setprio(0);
    }

    // ---- softmax(t), defer-max (log2 domain) ----
    float a0[4], a1[4];
#pragma unroll
    for (int r = 0; r < 4; ++r) { a0[r] = s0[r] * SC; a1[r] = s1[r] * SC; }
    float mx = fmaxf(fmaxf(fmaxf(a0[0], a0[1]), fmaxf(a0[2], a0[3])),
                     fmaxf(fmaxf(a1[0], a1[1]), fmaxf(a1[2], a1[3])));
    mx = fmaxf(mx, __shfl_xor(mx, 16));
    mx = fmaxf(mx, __shfl_xor(mx, 32));

    if (!__all(mx <= m + 8.0f)) {
      float mn = fmaxf(m, mx);
      float corr = exp2f(m - mn);
      m = mn; l *= corr;
#pragma unroll
      for (int r = 0; r < 4; ++r) {
        float cr = __shfl(corr, ((lane >> 2) & 12) + r);
#pragma unroll
        for (int f = 0; f < 16; ++f) o[f][r] *= cr;
      }
    }

    float e0[4], e1[4], rs;
#pragma unroll
    for (int r = 0; r < 4; ++r) { e0[r] = exp2f(a0[r] - m); e1[r] = exp2f(a1[r] - m); }
    rs = ((e0[0] + e0[1]) + (e0[2] + e0[3])) + ((e1[0] + e1[1]) + (e1[2] + e1[3]));
    rs += __shfl_xor(rs, 16);
    rs += __shfl_xor(rs, 32);
    l += rs;

    int A01 = pack_f16(e0[0], e0[1]);
    int A23 = pack_f16(e0[2], e0[3]);
    int B01 = pack_f16(e1[0], e1[1]);
    int B23 = pack_f16(e1[2], e1[3]);
    const int s1l = ((lane & 16) << 1) + lm;
    const int s2l = s1l + 16;
    int t0a = __shfl(A01, s1l), t0b = __shfl(B01, s1l);
    int t1a = __shfl(A23, s1l), t1b = __shfl(B23, s1l);
    int t2a = __shfl(A01, s2l), t2b = __shfl(B01, s2l);
    int t3a = __shfl(A23, s2l), t3b = __shfl(B23, s2l);
    union { int i[4]; half8 h; } pau;
    const bool hi = lane >= 32;
    pau.i[0] = hi ? t0b : t0a;
    pau.i[1] = hi ? t1b : t1a;
    pau.i[2] = hi ? t2b : t2a;
    pau.i[3] = hi ? t3b : t3a;
    paP = pau.h;

    BARRIER();
  }

  // ---- epilogue: PV(63) ----
  WAITVM0();
  BARRIER();
  {
    const f16* vbp = &lds[16384 + 8192];   // vbuf[63 & 1]
#pragma unroll
    for (int f = 0; f < 16; ++f) {
      int d = f * 16 + lm;
      half8 bv = *(const half8*)(vbp + d * 32 + ((g ^ ((d >> 1) & 3)) << 3));
      o[f] = MFMA_F16(paP, bv, o[f]);
    }
  }

  float inv[4];
#pragma unroll
  for (int r = 0; r < 4; ++r) inv[r] = 1.0f / __shfl(l, ((lane >> 2) & 12) + r);
#pragma unroll
  for (int f = 0; f < 16; ++f)
#pragma unroll
    for (int r = 0; r < 4; ++r)
      attn[(size_t)(b * 2048 + q0 + g * 4 + r) * 2048 + h * 256 + f * 16 + lm] =
          (f16)(o[f][r] * inv[r]);
}

// ======================= Spectral v6: cholT coalesced input, fused radix-2 stages =======================
__device__ inline float2 cmul(float2 a, float2 b) {
  return make_float2(a.x * b.x - a.y * b.y, a.x * b.y + a.y * b.x);
}
__device__ inline float2 cmulc(float2 a, float2 b) {
  return make_float2(a.x * b.x + a.y * b.y, a.y * b.x - a.x * b.y);
}
__device__ inline void qcube(float2& w, float2& x, float2& y, float2& z, float2 f) {
  w = cmul(w, f); x = cmul(x, f); y = cmul(y, f); z = cmul(z, f);
  float2 a2 = cmul(w, w);
  float2 sx = cmul(x, x), sy = cmul(y, y), sz = cmul(z, z);
  float2 s = make_float2(sx.x + sy.x + sz.x, sx.y + sy.y + sz.y);
  float2 t3 = make_float2(a2.x - 3.f * s.x, a2.y - 3.f * s.y);
  float2 cf = make_float2(3.f * a2.x - s.x, 3.f * a2.y - s.y);
  w = cmul(w, t3); x = cmul(cf, x); y = cmul(cf, y); z = cmul(cf, z);
}

__device__ inline int fftpos(int k) {
  int kp = k >> 1;
  return ((k & 1) << 10) | ((kp & 3) << 8) | ((kp & 12) << 4) | (kp & 48)
       | ((kp >> 4) & 12) | ((kp >> 8) & 3);
}

__global__ __launch_bounds__(256)
void spectral6(const f16* __restrict__ cholT, const float* __restrict__ xin,
               const float2* __restrict__ ftab, float* __restrict__ outp) {
  __shared__ __align__(16) float2 Z[2][2048];
  __shared__ float2 tw[1024];
  const int tid = threadIdx.x;
  const int b = blockIdx.x >> 8;
  const int qd = blockIdx.x & 255;
  const size_t c0 = (size_t)qd * 4;
  const f16* t0 = cholT + (c0 + 0) * 8192 + b * 2048;
  const f16* t1 = cholT + (c0 + 1) * 8192 + b * 2048;
  const f16* t2 = cholT + (c0 + 2) * 8192 + b * 2048;
  const f16* t3 = cholT + (c0 + 3) * 8192 + b * 2048;

  for (int j = tid; j < 1024; j += 256) {
    float ang = -6.2831853071795864769f * (float)j * (1.0f / 2048.0f);
    float sv, cv; sincosf(ang, &sv, &cv);
    tw[j] = make_float2(cv, sv);
  }
  // fused load + forward radix-2 (pairs (s, s+1024) thread-local; tw[s] written by same thread)
  for (int s = tid; s < 1024; s += 256) {
    float2 z0a = make_float2((float)t0[s], (float)t1[s]);
    float2 z1a = make_float2((float)t2[s], (float)t3[s]);
    float2 z0b = make_float2((float)t0[s + 1024], (float)t1[s + 1024]);
    float2 z1b = make_float2((float)t2[s + 1024], (float)t3[s + 1024]);
    float2 w = tw[s];
    Z[0][s] = make_float2(z0a.x + z0b.x, z0a.y + z0b.y);
    Z[0][s + 1024] = cmul(make_float2(z0a.x - z0b.x, z0a.y - z0b.y), w);
    Z[1][s] = make_float2(z1a.x + z1b.x, z1a.y + z1b.y);
    Z[1][s + 1024] = cmul(make_float2(z1a.x - z1b.x, z1a.y - z1b.y), w);
  }
  __syncthreads();

  // ---- forward radix-4 stages Q = 256,64,16,4,1 ----
#pragma unroll 1
  for (int lq = 8; lq >= 0; lq -= 2) {
    const int Q = 1 << lq, st = 512 >> lq;
#pragma unroll 1
    for (int it = 0; it < 4; ++it) {
      int gg = it * 256 + tid;
      int c = gg >> 9, bf = gg & 511;
      int j = bf & (Q - 1);
      int base = ((bf >> lq) << (lq + 2)) | j;
      float2 a = Z[c][base], bq = Z[c][base + Q];
      float2 cc = Z[c][base + 2 * Q], d = Z[c][base + 3 * Q];
      float2 t0_ = make_float2(a.x + cc.x, a.y + cc.y);
      float2 t1_ = make_float2(a.x - cc.x, a.y - cc.y);
      float2 t2_ = make_float2(bq.x + d.x, bq.y + d.y);
      float2 bd = make_float2(bq.x - d.x, bq.y - d.y);
      float2 t3_ = make_float2(bd.y, -bd.x);
      float2 y0 = make_float2(t0_.x + t2_.x, t0_.y + t2_.y);
      float2 y1 = make_float2(t1_.x + t3_.x, t1_.y + t3_.y);
      float2 y2 = make_float2(t0_.x - t2_.x, t0_.y - t2_.y);
      float2 y3 = make_float2(t1_.x - t3_.x, t1_.y - t3_.y);
      int i3 = 3 * j * st;
      float sg = (i3 & 1024) ? -1.f : 1.f;
      i3 &= 1023;
      Z[c][base] = y0;
      Z[c][base + Q] = cmul(y1, tw[j * st]);
      Z[c][base + 2 * Q] = cmul(y2, tw[2 * j * st]);
      float2 r3 = cmul(y3, tw[i3]);
      Z[c][base + 3 * Q] = make_float2(r3.x * sg, r3.y * sg);
    }
    __syncthreads();
  }

  // ---- middle: untangle (k, N-k), filter, quaternion cube, retangle ----
#pragma unroll 1
  for (int it = 0; it < 4; ++it) {
    int jj = it * 256 + tid;
    int nrep = (jj == 0) ? 2 : 1;
#pragma unroll 1
    for (int rep = 0; rep < nrep; ++rep) {
      int k  = (jj == 0) ? (rep ? 1024 : 0) : jj;
      int kn = (jj == 0) ? k : 2048 - jj;
      int p  = fftpos(k);
      int pp = fftpos(kn);
      float2 z0p = Z[0][p], z0q = Z[0][pp];
      float2 z1p = Z[1][p], z1q = Z[1][pp];
      float2 wk = make_float2(0.5f * (z0p.x + z0q.x), 0.5f * (z0p.y - z0q.y));
      float2 xk = make_float2(0.5f * (z0p.y + z0q.y), 0.5f * (z0q.x - z0p.x));
      float2 yk = make_float2(0.5f * (z1p.x + z1q.x), 0.5f * (z1p.y - z1q.y));
      float2 zk = make_float2(0.5f * (z1p.y + z1q.y), 0.5f * (z1q.x - z1p.x));
      float2 wn = make_float2(0.5f * (z0q.x + z0p.x), 0.5f * (z0q.y - z0p.y));
      float2 xn = make_float2(0.5f * (z0q.y + z0p.y), 0.5f * (z0p.x - z0q.x));
      float2 yn = make_float2(0.5f * (z1q.x + z1p.x), 0.5f * (z1q.y - z1p.y));
      float2 zn = make_float2(0.5f * (z1q.y + z1p.y), 0.5f * (z1p.x - z1q.x));
      float2 fk = ftab[k], fn = ftab[kn];
      qcube(wk, xk, yk, zk, fk);
      qcube(wn, xn, yn, zn, fn);
      Z[0][p]  = make_float2(0.5f * (wk.x + wn.x) - 0.5f * (xk.y - xn.y),
                             0.5f * (wk.y - wn.y) + 0.5f * (xk.x + xn.x));
      Z[0][pp] = make_float2(0.5f * (wn.x + wk.x) - 0.5f * (xn.y - xk.y),
                             0.5f * (wn.y - wk.y) + 0.5f * (xn.x + xk.x));
      Z[1][p]  = make_float2(0.5f * (yk.x + yn.x) - 0.5f * (zk.y - zn.y),
                             0.5f * (yk.y - yn.y) + 0.5f * (zk.x + zn.x));
      Z[1][pp] = make_float2(0.5f * (yn.x + yk.x) - 0.5f * (zn.y - zk.y),
                             0.5f * (yn.y - yk.y) + 0.5f * (zn.x + zk.x));
    }
  }
  __syncthreads();

  // ---- inverse radix-4 stages Q = 1,4,16,64,256 ----
#pragma unroll 1
  for (int lq = 0; lq <= 8; lq += 2) {
    const int Q = 1 << lq, st = 512 >> lq;
#pragma unroll 1
    for (int it = 0; it < 4; ++it) {
      int gg = it * 256 + tid;
      int c = gg >> 9, bf = gg & 511;
      int j = bf & (Q - 1);
      int base = ((bf >> lq) << (lq + 2)) | j;
      float2 a = Z[c][base];
      float2 bq = cmulc(Z[c][base + Q], tw[j * st]);
      float2 cc = cmulc(Z[c][base + 2 * Q], tw[2 * j * st]);
      int i3 = 3 * j * st;
      float sg = (i3 & 1024) ? -1.f : 1.f;
      i3 &= 1023;
      float2 d = cmulc(Z[c][base + 3 * Q], tw[i3]);
      d = make_float2(d.x * sg, d.y * sg);
      float2 t0_ = make_float2(a.x + cc.x, a.y + cc.y);
      float2 t1_ = make_float2(a.x - cc.x, a.y - cc.y);
      float2 t2_ = make_float2(bq.x + d.x, bq.y + d.y);
      float2 bd = make_float2(bq.x - d.x, bq.y - d.y);
      float2 t3_ = make_float2(-bd.y, bd.x);
      Z[c][base]         = make_float2(t0_.x + t2_.x, t0_.y + t2_.y);
      Z[c][base + Q]     = make_float2(t1_.x + t3_.x, t1_.y + t3_.y);
      Z[c][base + 2 * Q] = make_float2(t0_.x - t2_.x, t0_.y - t2_.y);
      Z[c][base + 3 * Q] = make_float2(t1_.x - t3_.x, t1_.y - t3_.y);
    }
    __syncthreads();
  }

  // ---- fused inverse radix-2 + x-mul + store ----
  const float* xb = xin + (size_t)b * 2048 * 1024;
  float* ob = outp + (size_t)b * 2048 * 1024;
  const float inv = 1.0f / 2048.0f;
  for (int j = tid; j < 1024; j += 256) {
    float2 wj = tw[j];
    float2 a0 = Z[0][j], bw0 = cmulc(Z[0][j + 1024], wj);
    float2 a1 = Z[1][j], bw1 = cmulc(Z[1][j + 1024], wj);
    float2 r0lo = make_float2(a0.x + bw0.x, a0.y + bw0.y);
    float2 r0hi = make_float2(a0.x - bw0.x, a0.y - bw0.y);
    float2 r1lo = make_float2(a1.x + bw1.x, a1.y + bw1.y);
    float2 r1hi = make_float2(a1.x - bw1.x, a1.y - bw1.y);
    float4 xlo = *(const float4*)(xb + (size_t)j * 1024 + c0);
    float4 xhi = *(const float4*)(xb + (size_t)(j + 1024) * 1024 + c0);
    float4 olo, ohi;
    olo.x = xlo.x * r0lo.x * inv;
    olo.y = xlo.y * r0lo.y * inv;
    olo.z = xlo.z * r1lo.x * inv;
    olo.w = xlo.w * r1lo.y * inv;
    ohi.x = xhi.x * r0hi.x * inv;
    ohi.y = xhi.y * r0hi.y * inv;
    ohi.z = xhi.z * r1hi.x * inv;
    ohi.w = xhi.w * r1hi.y * inv;
    *(float4*)(ob + (size_t)j * 1024 + c0) = olo;
    *(float4*)(ob + (size_t)(j + 1024) * 1024 + c0) = ohi;
  }
}

// ======================= launch =======================
extern "C" void kernel_launch(void* const* d_in, const int* in_sizes, int n_in,
                              void* d_out, int out_size, void* d_ws, size_t ws_size,
                              hipStream_t stream) {
  const float* x    = (const float*)d_in[0];
  const float* wqkv = (const float*)d_in[1];
  const float* bqkv = (const float*)d_in[2];
  const float* wout = (const float*)d_in[3];
  const float* bout = (const float*)d_in[4];
  const float* w1   = (const float*)d_in[5];
  const float* b1   = (const float*)d_in[6];
  const float* w2   = (const float*)d_in[7];
  const float* b2   = (const float*)d_in[8];
  float* out = (float*)d_out;
  char* wsb = (char*)d_ws;
  const size_t MB = 1048576;

  // ws: xf 16@0 | wqf 8@16 | wcat 8@24 | qkvF 48@32 | VtF 16@80 | cat 32@96
  //   | cholT 16@128 | ftab @145
  f16*   xf    = (f16*)(wsb);
  f16*   wqf   = (f16*)(wsb + 16 * MB);
  f16*   wcat  = (f16*)(wsb + 24 * MB);
  f16*   qkvF  = (f16*)(wsb + 32 * MB);
  f16*   VtF   = (f16*)(wsb + 80 * MB);
  f16*   cat   = (f16*)(wsb + 96 * MB);
  f16*   cholT = (f16*)(wsb + 128 * MB);
  float2* ftab = (float2*)(wsb + 145 * MB);

  filt_init<<<8, 256, 0, stream>>>(ftab);
  conv_all<<<7168, 256, 0, stream>>>(x, wqkv, w1, wout, w2, xf);

  // GEMM A: [qkv | gelu(h)] = xf @ [Wqkv;W1]^T; V written transposed to VtF
  gemm_f16<3><<<dim3(32, 64), 256, 0, stream>>>(xf, wqf, bqkv, b1, qkvF, cat, VtF, 4096, 1024);
  flash_f16<<<256, 512, 0, stream>>>(qkvF, VtF, cat);   // writes cat low half
  // GEMM B: cholT = ([attn|h] @ [1.8Wout|0.2W2]^T + 1.8bout + 0.2b2)^T
  gemm_f16<4><<<dim3(8, 64), 256, 0, stream>>>(cat, wcat, bout, b2, cholT, nullptr, nullptr, 1024, 2048);
  spectral6<<<1024, 256, 0, stream>>>(cholT, x, ftab, out);
}

// Round 13
// 341.605 us; speedup vs baseline: 1.1190x; 1.0324x over previous
//
#include <hip/hip_runtime.h>
#include <cstdint>

// B=4, S=2048, E=1024, H=4, DH=256, DQ=256
typedef _Float16 f16;
typedef unsigned short u16;
typedef __attribute__((ext_vector_type(8))) _Float16 half8;
typedef __attribute__((ext_vector_type(4))) _Float16 half4;
typedef __attribute__((ext_vector_type(2))) __fp16 fp16x2;
typedef __attribute__((ext_vector_type(4))) float f32x4;

#define MFMA_F16(a, b, c) __builtin_amdgcn_mfma_f32_16x16x32_f16(a, b, c, 0, 0, 0)

#define WAITVM8() asm volatile("s_waitcnt vmcnt(8)" ::: "memory")
#define WAITVM4() asm volatile("s_waitcnt vmcnt(4)" ::: "memory")
#define WAITVM0() asm volatile("s_waitcnt vmcnt(0)" ::: "memory")
#define BARRIER() do { asm volatile("" ::: "memory"); __builtin_amdgcn_s_barrier(); \
                       asm volatile("" ::: "memory"); } while (0)

#define SCQ 0.09016844005555896f   // log2(e)/16, folded into Q projection

__device__ inline void stage16(const void* g, void* l) {
#if defined(__has_builtin) && __has_builtin(__builtin_amdgcn_global_load_lds)
  __builtin_amdgcn_global_load_lds(
      (const __attribute__((address_space(1))) unsigned*)g,
      (__attribute__((address_space(3))) unsigned*)l, 16, 0, 0);
#else
  *(int4*)l = *(const int4*)g;
#endif
}

__device__ inline int pack_f16(float a, float b) {
#if defined(__has_builtin) && __has_builtin(__builtin_amdgcn_cvt_pkrtz)
  union { fp16x2 h; int i; } u;
  u.h = __builtin_amdgcn_cvt_pkrtz(a, b);
  return u.i;
#else
  union { f16 h[2]; int i; } u;
  u.h[0] = (f16)a; u.h[1] = (f16)b;
  return u.i;
#endif
}

// ======================= fused fp32 -> fp16 conversion + weight layout + tables =======================
// data blocks 0..7167; table blocks 7168..7183 fill ftab[2048] + twtab[1024]
__global__ __launch_bounds__(256)
void conv_all(const float* __restrict__ x, const float* __restrict__ wqkv,
              const float* __restrict__ w1, const float* __restrict__ wout,
              const float* __restrict__ w2, f16* __restrict__ dst,
              float2* __restrict__ tab) {
  if (blockIdx.x >= 7168) {
    int kk = (blockIdx.x - 7168) * 256 + threadIdx.x;
    if (kk < 2048) {
      float s, c;
      sincosf(1.5f * atanf(logf((float)kk + 1e-10f)), &s, &c);
      tab[kk] = make_float2(c, s);
    } else if (kk < 3072) {
      int j = kk - 2048;
      float s, c;
      sincosf(-6.2831853071795864769f * (float)j * (1.0f / 2048.0f), &s, &c);
      tab[kk] = make_float2(c, s);
    }
    return;
  }
  int i = (blockIdx.x * 256 + threadIdx.x) * 8;
  const float* src; size_t dofs; float sc = 1.0f;
  if (i < 8388608)       { src = x + i;               dofs = i; }
  else if (i < 11534336) {
    int t = i - 8388608;
    src = wqkv + t; dofs = i;
    if ((t >> 10) < 1024) sc = SCQ;        // Q rows pre-scaled by log2(e)/16
  }
  else if (i < 12582912) { src = w1 + (i - 11534336);  dofs = i; }
  else if (i < 13631488) {
    int t = i - 12582912; int j = t >> 10, k = t & 1023;
    src = wout + t; dofs = 12582912 + (size_t)j * 2048 + k; sc = 1.8f;
  } else {
    int t = i - 13631488; int j = t >> 10, k = t & 1023;
    src = w2 + t; dofs = 13631488 - 1048576 + (size_t)j * 2048 + 1024 + k; sc = 0.2f;
  }
  float4 a = *(const float4*)src;
  float4 b = *(const float4*)(src + 4);
  half8 h;
  h[0] = (f16)(a.x * sc); h[1] = (f16)(a.y * sc); h[2] = (f16)(a.z * sc); h[3] = (f16)(a.w * sc);
  h[4] = (f16)(b.x * sc); h[5] = (f16)(b.y * sc); h[6] = (f16)(b.z * sc); h[7] = (f16)(b.w * sc);
  *(half8*)(dst + dofs) = h;
}

// ======================= fp16 MFMA GEMM, counted-vmcnt 2-phase, XCD-swizzled =======================
// EPI=3: A=xf, W=[Wqkv;W1] N=4096:
//   n0<2048  -> +bqkv (Q part: bias*SCQ) -> qkvF (f16, stride 3072)
//   n0<3072  -> +bqkv -> transposed via LDS -> Vt
//   n0>=3072 -> +b1, GELU -> cat[row][1024+c'] (stride 2048)
// EPI=4: A=cat(K=2048), W=Wcat: cholT[1024][8192] f16 = (acc + 1.8*bout + 0.2*b2)^T via LDS
template<int EPI>
__global__ __launch_bounds__(256, 2)
void gemm_f16(const f16* __restrict__ A, const f16* __restrict__ W,
              const float* __restrict__ bias0, const float* __restrict__ bias1,
              void* __restrict__ out0, void* __restrict__ out1,
              f16* __restrict__ Vt, int N, int K) {
  __shared__ __align__(16) f16 lds[2][16384];
  const int tid = threadIdx.x;
  const int lane = tid & 63, w = tid >> 6;
  const int g = lane >> 4, lm = lane & 15;
  const int wr = w >> 1, wc = w & 1;
  const int nwg = gridDim.x * gridDim.y;
  const int flat = blockIdx.y * gridDim.x + blockIdx.x;
  const int logical = (flat & 7) * (nwg >> 3) + (flat >> 3);
  const int bx = logical % gridDim.x, by = logical / gridDim.x;
  const int m0 = by * 128, n0 = bx * 128;

  const f16* src[8];
#pragma unroll
  for (int j = 0; j < 8; ++j) {
    int u = j * 256 + tid;
    if (u < 1024) {
      int row = u >> 3, s = u & 7;
      src[j] = A + (size_t)(m0 + row) * K + ((s ^ (row & 7)) << 3);
    } else {
      int v = u - 1024;
      int row = v >> 3, s = v & 7;
      src[j] = W + (size_t)(n0 + row) * K + ((s ^ (row & 7)) << 3);
    }
  }

  f32x4 acc[4][4];
#pragma unroll
  for (int mt = 0; mt < 4; ++mt)
#pragma unroll
    for (int nt = 0; nt < 4; ++nt) acc[mt][nt] = (f32x4){0.f, 0.f, 0.f, 0.f};

#pragma unroll
  for (int j = 0; j < 8; ++j) stage16(src[j], &lds[0][(j * 256 + tid) * 8]);
  __syncthreads();

  const int KT = K >> 6;
#pragma unroll 1
  for (int t = 0; t < KT; ++t) {
    const f16* bufA = lds[t & 1];
    const f16* bufB = bufA + 8192;
    if (t + 1 < KT) {
#pragma unroll
      for (int j = 0; j < 8; ++j) {
        src[j] += 64;
        stage16(src[j], &lds[(t + 1) & 1][(j * 256 + tid) * 8]);
      }
      WAITVM8();
    } else {
      WAITVM0();
    }
    BARRIER();
#pragma unroll
    for (int ks = 0; ks < 2; ++ks) {
      half8 a[4], b[4];
#pragma unroll
      for (int mt = 0; mt < 4; ++mt) {
        int row = wr * 64 + mt * 16 + lm;
        a[mt] = *(const half8*)(bufA + row * 64 + (((ks * 4 + g) ^ (row & 7)) << 3));
      }
#pragma unroll
      for (int nt = 0; nt < 4; ++nt) {
        int row = wc * 64 + nt * 16 + lm;
        b[nt] = *(const half8*)(bufB + row * 64 + (((ks * 4 + g) ^ (row & 7)) << 3));
      }
#pragma unroll
      for (int mt = 0; mt < 4; ++mt)
#pragma unroll
        for (int nt = 0; nt < 4; ++nt)
          acc[mt][nt] = MFMA_F16(a[mt], b[nt], acc[mt][nt]);
    }
    BARRIER();
  }

  const int crow = m0 + wr * 64 + g * 4;
  const int ccol = n0 + wc * 64 + lm;
  if (EPI == 3) {
    if (n0 < 2048) {                       // Q,K region -> qkvF rows
      f16* qk = (f16*)out0;
      const float bsc = (n0 < 1024) ? SCQ : 1.0f;
#pragma unroll
      for (int nt = 0; nt < 4; ++nt) {
        float bb = bias0[ccol + nt * 16] * bsc;
#pragma unroll
        for (int mt = 0; mt < 4; ++mt)
#pragma unroll
          for (int r = 0; r < 4; ++r)
            qk[(size_t)(crow + mt * 16 + r) * 3072 + ccol + nt * 16] =
                (f16)(acc[mt][nt][r] + bb);
      }
    } else if (n0 < 3072) {                // V region -> transposed Vt via LDS
      f16* ldsT = (f16*)lds;
#pragma unroll
      for (int nt = 0; nt < 4; ++nt) {
        float bb = bias0[ccol + nt * 16];
        int c = wc * 64 + nt * 16 + lm;
#pragma unroll
        for (int mt = 0; mt < 4; ++mt) {
          int r = wr * 64 + mt * 16 + g * 4;
#pragma unroll
          for (int rr = 0; rr < 4; ++rr)
            ldsT[c * 136 + r + rr] = (f16)(acc[mt][nt][rr] + bb);
        }
      }
      BARRIER();
      const int vbase0 = n0 - 2048;
      const int b = m0 >> 11, srow = m0 & 2047;
#pragma unroll
      for (int it = 0; it < 8; ++it) {
        int id = it * 256 + tid;
        int c = id >> 4, rb = id & 15;
        int vcol = vbase0 + c;
        int h = vcol >> 8, d = vcol & 255;
        half8 v = *(half8*)&ldsT[c * 136 + rb * 8];
        *(half8*)&Vt[(((size_t)(b * 4 + h)) * 256 + d) * 2048 + srow + rb * 8] = v;
      }
    } else {                               // h region -> GELU -> cat high half
      f16* cat = (f16*)out1;
      const int hc = ccol - 3072;
#pragma unroll
      for (int nt = 0; nt < 4; ++nt) {
        float bb = bias1[hc + nt * 16];
#pragma unroll
        for (int mt = 0; mt < 4; ++mt)
#pragma unroll
          for (int r = 0; r < 4; ++r) {
            float v = acc[mt][nt][r] + bb;
            v = 0.5f * v * (1.0f + erff(v * 0.70710678118654752f));
            cat[(size_t)(crow + mt * 16 + r) * 2048 + 1024 + hc + nt * 16] = (f16)v;
          }
      }
    }
  } else {                                 // EPI 4: cholT (transposed) via LDS
    f16* ldsT = (f16*)lds;
#pragma unroll
    for (int nt = 0; nt < 4; ++nt) {
      float bb = 1.8f * bias0[ccol + nt * 16] + 0.2f * bias1[ccol + nt * 16];
      int c = wc * 64 + nt * 16 + lm;
#pragma unroll
      for (int mt = 0; mt < 4; ++mt) {
        int r = wr * 64 + mt * 16 + g * 4;
#pragma unroll
        for (int rr = 0; rr < 4; ++rr)
          ldsT[c * 136 + r + rr] = (f16)(acc[mt][nt][rr] + bb);
      }
    }
    BARRIER();
    f16* ch = (f16*)out0;
#pragma unroll
    for (int it = 0; it < 8; ++it) {
      int id = it * 256 + tid;
      int c = id >> 4, rb = id & 15;
      half8 v = *(half8*)&ldsT[c * 136 + rb * 8];
      *(half8*)&ch[(size_t)(n0 + c) * 8192 + m0 + rb * 8] = v;
    }
  }
}

// ======================= fp16 flash attention v8: TKV=64, 32 iters, halved barriers =======================
// LDS: K[2][64][256] @0 (2x32KB), V[2][256][64] @32768 (2x32KB) = 128KB -> 1 block/CU, 8 waves.
// Per iter: stage K(t+1) (4 units) + V(t) (4); QK(t) 32 MFMA; PV(t-1) 32 MFMA; softmax over 64 kv.
__global__ __launch_bounds__(512, 1)
void flash_f16(const f16* __restrict__ qkv, const f16* __restrict__ Vt,
               f16* __restrict__ attn) {
  __shared__ __align__(16) f16 lds[65536];
  const int tid = threadIdx.x;
  const int lane = tid & 63, w = tid >> 6;   // w 0..7
  const int g = lane >> 4, lm = lane & 15;
  const int raw = blockIdx.x;                // 256 blocks
  const int bh = (raw & 7) * 2 + (raw >> 7);
  const int qt = (raw >> 3) & 15;
  const int b = bh >> 2, h = bh & 3;
  const int q0 = qt * 128 + w * 16;

  half8 qf[8];   // Q rows pre-scaled by SCQ (folded into Wqkv/bqkv)
  {
    const f16* qp = qkv + (size_t)(b * 2048 + q0 + lm) * 3072 + h * 256 + g * 8;
#pragma unroll
    for (int c = 0; c < 8; ++c) qf[c] = *(const half8*)(qp + c * 32);
  }

  const f16* kbase = qkv + (size_t)b * 2048 * 3072 + 1024 + h * 256;
  const f16* vbase = Vt + (size_t)bh * 256 * 2048;
  int kofs[4], vofs[4];
#pragma unroll
  for (int j = 0; j < 4; ++j) {
    int u = j * 512 + tid;
    int kv = u >> 5, s = u & 31;
    kofs[j] = kv * 3072 + ((s ^ (kv & 7)) << 3);
    int d = u >> 3, sl = u & 7;
    vofs[j] = d * 2048 + ((sl ^ (d & 7)) << 3);
  }

  f32x4 o[16];
#pragma unroll
  for (int f = 0; f < 16; ++f) o[f] = (f32x4){0.f, 0.f, 0.f, 0.f};
  float m = -3e38f, l = 0.f;
  half8 paP0 = (half8){0, 0, 0, 0, 0, 0, 0, 0};
  half8 paP1 = (half8){0, 0, 0, 0, 0, 0, 0, 0};

  // prologue: K(0) -> kbuf0
#pragma unroll
  for (int j = 0; j < 4; ++j) stage16(kbase + kofs[j], &lds[(j * 512 + tid) * 8]);

#pragma unroll 1
  for (int t = 0; t < 32; ++t) {
    const int cb_ = t & 1;
    if (t < 31) {
      const int kt = (t + 1) * 196608;
#pragma unroll
      for (int j = 0; j < 4; ++j)
        stage16(kbase + kofs[j] + kt, &lds[(cb_ ^ 1) * 16384 + (j * 512 + tid) * 8]);
    }
    {
      const int vt_ = t * 64;
#pragma unroll
      for (int j = 0; j < 4; ++j)
        stage16(vbase + vofs[j] + vt_, &lds[32768 + cb_ * 16384 + (j * 512 + tid) * 8]);
    }
    if (t < 31) { WAITVM8(); } else { WAITVM4(); }   // K(t),V(t-1) landed; newest in flight
    BARRIER();

    const f16* kb = &lds[cb_ * 16384];

    // ---- QK(t): S^T[64 kv][16 q] = mfma(A=K, B=Q), 4 acc chains ----
    f32x4 s0 = {0.f, 0.f, 0.f, 0.f}, s1 = {0.f, 0.f, 0.f, 0.f};
    f32x4 s2 = {0.f, 0.f, 0.f, 0.f}, s3 = {0.f, 0.f, 0.f, 0.f};
    __builtin_amdgcn_s_setprio(1);
#pragma unroll
    for (int c = 0; c < 8; ++c) {
      int slot = ((c * 4 + g) ^ (lm & 7)) << 3;
      const f16* kr = kb + lm * 256 + slot;
      half8 b0 = *(const half8*)(kr);
      half8 b1 = *(const half8*)(kr + 16 * 256);
      half8 b2 = *(const half8*)(kr + 32 * 256);
      half8 b3 = *(const half8*)(kr + 48 * 256);
      s0 = MFMA_F16(b0, qf[c], s0);
      s1 = MFMA_F16(b1, qf[c], s1);
      s2 = MFMA_F16(b2, qf[c], s2);
      s3 = MFMA_F16(b3, qf[c], s3);
    }
    __builtin_amdgcn_s_setprio(0);

    // ---- PV(t-1): 32 MFMA, overlaps softmax(t)'s VALU ----
    if (t > 0) {
      const f16* vbp = &lds[32768 + (cb_ ^ 1) * 16384];
      __builtin_amdgcn_s_setprio(1);
#pragma unroll
      for (int f = 0; f < 16; ++f) {
        int d = f * 16 + lm;
        const f16* vr = vbp + d * 64;
        half8 bv0 = *(const half8*)(vr + ((g ^ (d & 7)) << 3));
        half8 bv1 = *(const half8*)(vr + (((4 + g) ^ (d & 7)) << 3));
        o[f] = MFMA_F16(paP0, bv0, o[f]);
        o[f] = MFMA_F16(paP1, bv1, o[f]);
      }
      __builtin_amdgcn_s_setprio(0);
    }

    // ---- softmax(t) over 64 kv (scores already in log2 domain), defer-max ----
    float mx = fmaxf(fmaxf(fmaxf(s0[0], s0[1]), fmaxf(s0[2], s0[3])),
                     fmaxf(fmaxf(s1[0], s1[1]), fmaxf(s1[2], s1[3])));
    mx = fmaxf(mx, fmaxf(fmaxf(fmaxf(s2[0], s2[1]), fmaxf(s2[2], s2[3])),
                         fmaxf(fmaxf(s3[0], s3[1]), fmaxf(s3[2], s3[3]))));
    mx = fmaxf(mx, __shfl_xor(mx, 16));
    mx = fmaxf(mx, __shfl_xor(mx, 32));

    if (!__all(mx <= m + 8.0f)) {
      float mn = fmaxf(m, mx);
      float corr = exp2f(m - mn);
      m = mn; l *= corr;
#pragma unroll
      for (int r = 0; r < 4; ++r) {
        float cr = __shfl(corr, ((lane >> 2) & 12) + r);
#pragma unroll
        for (int f = 0; f < 16; ++f) o[f][r] *= cr;
      }
    }

    float e0[4], e1[4], e2[4], e3[4];
#pragma unroll
    for (int r = 0; r < 4; ++r) {
      e0[r] = exp2f(s0[r] - m);
      e1[r] = exp2f(s1[r] - m);
      e2[r] = exp2f(s2[r] - m);
      e3[r] = exp2f(s3[r] - m);
    }
    float rs = ((e0[0] + e0[1]) + (e0[2] + e0[3])) + ((e1[0] + e1[1]) + (e1[2] + e1[3]))
             + ((e2[0] + e2[1]) + (e2[2] + e2[3])) + ((e3[0] + e3[1]) + (e3[2] + e3[3]));
    rs += __shfl_xor(rs, 16);
    rs += __shfl_xor(rs, 32);
    l += rs;

    // ---- P(t) -> two A-fragments (kv 0..31 and 32..63), register-only ----
    const int s1l = ((lane & 16) << 1) + lm;
    const int s2l = s1l + 16;
    const bool hi = lane >= 32;
    {
      int A01 = pack_f16(e0[0], e0[1]);
      int A23 = pack_f16(e0[2], e0[3]);
      int B01 = pack_f16(e1[0], e1[1]);
      int B23 = pack_f16(e1[2], e1[3]);
      int t0a = __shfl(A01, s1l), t0b = __shfl(B01, s1l);
      int t1a = __shfl(A23, s1l), t1b = __shfl(B23, s1l);
      int t2a = __shfl(A01, s2l), t2b = __shfl(B01, s2l);
      int t3a = __shfl(A23, s2l), t3b = __shfl(B23, s2l);
      union { int i[4]; half8 h; } pau;
      pau.i[0] = hi ? t0b : t0a;
      pau.i[1] = hi ? t1b : t1a;
      pau.i[2] = hi ? t2b : t2a;
      pau.i[3] = hi ? t3b : t3a;
      paP0 = pau.h;
    }
    {
      int A01 = pack_f16(e2[0], e2[1]);
      int A23 = pack_f16(e2[2], e2[3]);
      int B01 = pack_f16(e3[0], e3[1]);
      int B23 = pack_f16(e3[2], e3[3]);
      int t0a = __shfl(A01, s1l), t0b = __shfl(B01, s1l);
      int t1a = __shfl(A23, s1l), t1b = __shfl(B23, s1l);
      int t2a = __shfl(A01, s2l), t2b = __shfl(B01, s2l);
      int t3a = __shfl(A23, s2l), t3b = __shfl(B23, s2l);
      union { int i[4]; half8 h; } pau;
      pau.i[0] = hi ? t0b : t0a;
      pau.i[1] = hi ? t1b : t1a;
      pau.i[2] = hi ? t2b : t2a;
      pau.i[3] = hi ? t3b : t3a;
      paP1 = pau.h;
    }

    BARRIER();   // all waves done reading kbuf[t&1] / vbuf[(t-1)&1]
  }

  // ---- epilogue: PV(31) ----
  WAITVM0();
  BARRIER();
  {
    const f16* vbp = &lds[32768 + 16384];   // vbuf[31 & 1 = 1]
#pragma unroll
    for (int f = 0; f < 16; ++f) {
      int d = f * 16 + lm;
      const f16* vr = vbp + d * 64;
      half8 bv0 = *(const half8*)(vr + ((g ^ (d & 7)) << 3));
      half8 bv1 = *(const half8*)(vr + (((4 + g) ^ (d & 7)) << 3));
      o[f] = MFMA_F16(paP0, bv0, o[f]);
      o[f] = MFMA_F16(paP1, bv1, o[f]);
    }
  }

  float inv[4];
#pragma unroll
  for (int r = 0; r < 4; ++r) inv[r] = 1.0f / __shfl(l, ((lane >> 2) & 12) + r);
#pragma unroll
  for (int f = 0; f < 16; ++f)
#pragma unroll
    for (int r = 0; r < 4; ++r)
      attn[(size_t)(b * 2048 + q0 + g * 4 + r) * 2048 + h * 256 + f * 16 + lm] =
          (f16)(o[f][r] * inv[r]);
}

// ======================= Spectral v7: cholT coalesced, fused radix-2, table twiddles =======================
__device__ inline float2 cmul(float2 a, float2 b) {
  return make_float2(a.x * b.x - a.y * b.y, a.x * b.y + a.y * b.x);
}
__device__ inline float2 cmulc(float2 a, float2 b) {
  return make_float2(a.x * b.x + a.y * b.y, a.y * b.x - a.x * b.y);
}
__device__ inline void qcube(float2& w, float2& x, float2& y, float2& z, float2 f) {
  w = cmul(w, f); x = cmul(x, f); y = cmul(y, f); z = cmul(z, f);
  float2 a2 = cmul(w, w);
  float2 sx = cmul(x, x), sy = cmul(y, y), sz = cmul(z, z);
  float2 s = make_float2(sx.x + sy.x + sz.x, sx.y + sy.y + sz.y);
  float2 t3 = make_float2(a2.x - 3.f * s.x, a2.y - 3.f * s.y);
  float2 cf = make_float2(3.f * a2.x - s.x, 3.f * a2.y - s.y);
  w = cmul(w, t3); x = cmul(cf, x); y = cmul(cf, y); z = cmul(cf, z);
}

__device__ inline int fftpos(int k) {
  int kp = k >> 1;
  return ((k & 1) << 10) | ((kp & 3) << 8) | ((kp & 12) << 4) | (kp & 48)
       | ((kp >> 4) & 12) | ((kp >> 8) & 3);
}

__global__ __launch_bounds__(256)
void spectral7(const f16* __restrict__ cholT, const float* __restrict__ xin,
               const float2* __restrict__ tab, float* __restrict__ outp) {
  __shared__ __align__(16) float2 Z[2][2048];
  __shared__ float2 tw[1024];
  const int tid = threadIdx.x;
  const int b = blockIdx.x >> 8;
  const int qd = blockIdx.x & 255;
  const size_t c0 = (size_t)qd * 4;
  const f16* t0 = cholT + (c0 + 0) * 8192 + b * 2048;
  const f16* t1 = cholT + (c0 + 1) * 8192 + b * 2048;
  const f16* t2 = cholT + (c0 + 2) * 8192 + b * 2048;
  const f16* t3 = cholT + (c0 + 3) * 8192 + b * 2048;
  const float2* ftab = tab;
  const float2* twt = tab + 2048;

  for (int j = tid; j < 1024; j += 256) tw[j] = twt[j];
  // fused load + forward radix-2
  for (int s = tid; s < 1024; s += 256) {
    float2 z0a = make_float2((float)t0[s], (float)t1[s]);
    float2 z1a = make_float2((float)t2[s], (float)t3[s]);
    float2 z0b = make_float2((float)t0[s + 1024], (float)t1[s + 1024]);
    float2 z1b = make_float2((float)t2[s + 1024], (float)t3[s + 1024]);
    float2 w = twt[s];
    Z[0][s] = make_float2(z0a.x + z0b.x, z0a.y + z0b.y);
    Z[0][s + 1024] = cmul(make_float2(z0a.x - z0b.x, z0a.y - z0b.y), w);
    Z[1][s] = make_float2(z1a.x + z1b.x, z1a.y + z1b.y);
    Z[1][s + 1024] = cmul(make_float2(z1a.x - z1b.x, z1a.y - z1b.y), w);
  }
  __syncthreads();

#pragma unroll 1
  for (int lq = 8; lq >= 0; lq -= 2) {
    const int Q = 1 << lq, st = 512 >> lq;
#pragma unroll 1
    for (int it = 0; it < 4; ++it) {
      int gg = it * 256 + tid;
      int c = gg >> 9, bf = gg & 511;
      int j = bf & (Q - 1);
      int base = ((bf >> lq) << (lq + 2)) | j;
      float2 a = Z[c][base], bq = Z[c][base + Q];
      float2 cc = Z[c][base + 2 * Q], d = Z[c][base + 3 * Q];
      float2 t0_ = make_float2(a.x + cc.x, a.y + cc.y);
      float2 t1_ = make_float2(a.x - cc.x, a.y - cc.y);
      float2 t2_ = make_float2(bq.x + d.x, bq.y + d.y);
      float2 bd = make_float2(bq.x - d.x, bq.y - d.y);
      float2 t3_ = make_float2(bd.y, -bd.x);
      float2 y0 = make_float2(t0_.x + t2_.x, t0_.y + t2_.y);
      float2 y1 = make_float2(t1_.x + t3_.x, t1_.y + t3_.y);
      float2 y2 = make_float2(t0_.x - t2_.x, t0_.y - t2_.y);
      float2 y3 = make_float2(t1_.x - t3_.x, t1_.y - t3_.y);
      int i3 = 3 * j * st;
      float sg = (i3 & 1024) ? -1.f : 1.f;
      i3 &= 1023;
      Z[c][base] = y0;
      Z[c][base + Q] = cmul(y1, tw[j * st]);
      Z[c][base + 2 * Q] = cmul(y2, tw[2 * j * st]);
      float2 r3 = cmul(y3, tw[i3]);
      Z[c][base + 3 * Q] = make_float2(r3.x * sg, r3.y * sg);
    }
    __syncthreads();
  }

#pragma unroll 1
  for (int it = 0; it < 4; ++it) {
    int jj = it * 256 + tid;
    int nrep = (jj == 0) ? 2 : 1;
#pragma unroll 1
    for (int rep = 0; rep < nrep; ++rep) {
      int k  = (jj == 0) ? (rep ? 1024 : 0) : jj;
      int kn = (jj == 0) ? k : 2048 - jj;
      int p  = fftpos(k);
      int pp = fftpos(kn);
      float2 z0p = Z[0][p], z0q = Z[0][pp];
      float2 z1p = Z[1][p], z1q = Z[1][pp];
      float2 wk = make_float2(0.5f * (z0p.x + z0q.x), 0.5f * (z0p.y - z0q.y));
      float2 xk = make_float2(0.5f * (z0p.y + z0q.y), 0.5f * (z0q.x - z0p.x));
      float2 yk = make_float2(0.5f * (z1p.x + z1q.x), 0.5f * (z1p.y - z1q.y));
      float2 zk = make_float2(0.5f * (z1p.y + z1q.y), 0.5f * (z1q.x - z1p.x));
      float2 wn = make_float2(0.5f * (z0q.x + z0p.x), 0.5f * (z0q.y - z0p.y));
      float2 xn = make_float2(0.5f * (z0q.y + z0p.y), 0.5f * (z0p.x - z0q.x));
      float2 yn = make_float2(0.5f * (z1q.x + z1p.x), 0.5f * (z1q.y - z1p.y));
      float2 zn = make_float2(0.5f * (z1q.y + z1p.y), 0.5f * (z1p.x - z1q.x));
      float2 fk = ftab[k], fn = ftab[kn];
      qcube(wk, xk, yk, zk, fk);
      qcube(wn, xn, yn, zn, fn);
      Z[0][p]  = make_float2(0.5f * (wk.x + wn.x) - 0.5f * (xk.y - xn.y),
                             0.5f * (wk.y - wn.y) + 0.5f * (xk.x + xn.x));
      Z[0][pp] = make_float2(0.5f * (wn.x + wk.x) - 0.5f * (xn.y - xk.y),
                             0.5f * (wn.y - wk.y) + 0.5f * (xn.x + xk.x));
      Z[1][p]  = make_float2(0.5f * (yk.x + yn.x) - 0.5f * (zk.y - zn.y),
                             0.5f * (yk.y - yn.y) + 0.5f * (zk.x + zn.x));
      Z[1][pp] = make_float2(0.5f * (yn.x + yk.x) - 0.5f * (zn.y - zk.y),
                             0.5f * (yn.y - yk.y) + 0.5f * (zn.x + zk.x));
    }
  }
  __syncthreads();

#pragma unroll 1
  for (int lq = 0; lq <= 8; lq += 2) {
    const int Q = 1 << lq, st = 512 >> lq;
#pragma unroll 1
    for (int it = 0; it < 4; ++it) {
      int gg = it * 256 + tid;
      int c = gg >> 9, bf = gg & 511;
      int j = bf & (Q - 1);
      int base = ((bf >> lq) << (lq + 2)) | j;
      float2 a = Z[c][base];
      float2 bq = cmulc(Z[c][base + Q], tw[j * st]);
      float2 cc = cmulc(Z[c][base + 2 * Q], tw[2 * j * st]);
      int i3 = 3 * j * st;
      float sg = (i3 & 1024) ? -1.f : 1.f;
      i3 &= 1023;
      float2 d = cmulc(Z[c][base + 3 * Q], tw[i3]);
      d = make_float2(d.x * sg, d.y * sg);
      float2 t0_ = make_float2(a.x + cc.x, a.y + cc.y);
      float2 t1_ = make_float2(a.x - cc.x, a.y - cc.y);
      float2 t2_ = make_float2(bq.x + d.x, bq.y + d.y);
      float2 bd = make_float2(bq.x - d.x, bq.y - d.y);
      float2 t3_ = make_float2(-bd.y, bd.x);
      Z[c][base]         = make_float2(t0_.x + t2_.x, t0_.y + t2_.y);
      Z[c][base + Q]     = make_float2(t1_.x + t3_.x, t1_.y + t3_.y);
      Z[c][base + 2 * Q] = make_float2(t0_.x - t2_.x, t0_.y - t2_.y);
      Z[c][base + 3 * Q] = make_float2(t1_.x - t3_.x, t1_.y - t3_.y);
    }
    __syncthreads();
  }

  // fused inverse radix-2 + x-mul + store
  const float* xb = xin + (size_t)b * 2048 * 1024;
  float* ob = outp + (size_t)b * 2048 * 1024;
  const float inv = 1.0f / 2048.0f;
  for (int j = tid; j < 1024; j += 256) {
    float2 wj = tw[j];
    float2 a0 = Z[0][j], bw0 = cmulc(Z[0][j + 1024], wj);
    float2 a1 = Z[1][j], bw1 = cmulc(Z[1][j + 1024], wj);
    float2 r0lo = make_float2(a0.x + bw0.x, a0.y + bw0.y);
    float2 r0hi = make_float2(a0.x - bw0.x, a0.y - bw0.y);
    float2 r1lo = make_float2(a1.x + bw1.x, a1.y + bw1.y);
    float2 r1hi = make_float2(a1.x - bw1.x, a1.y - bw1.y);
    float4 xlo = *(const float4*)(xb + (size_t)j * 1024 + c0);
    float4 xhi = *(const float4*)(xb + (size_t)(j + 1024) * 1024 + c0);
    float4 olo, ohi;
    olo.x = xlo.x * r0lo.x * inv;
    olo.y = xlo.y * r0lo.y * inv;
    olo.z = xlo.z * r1lo.x * inv;
    olo.w = xlo.w * r1lo.y * inv;
    ohi.x = xhi.x * r0hi.x * inv;
    ohi.y = xhi.y * r0hi.y * inv;
    ohi.z = xhi.z * r1hi.x * inv;
    ohi.w = xhi.w * r1hi.y * inv;
    *(float4*)(ob + (size_t)j * 1024 + c0) = olo;
    *(float4*)(ob + (size_t)(j + 1024) * 1024 + c0) = ohi;
  }
}

// ======================= launch =======================
extern "C" void kernel_launch(void* const* d_in, const int* in_sizes, int n_in,
                              void* d_out, int out_size, void* d_ws, size_t ws_size,
                              hipStream_t stream) {
  const float* x    = (const float*)d_in[0];
  const float* wqkv = (const float*)d_in[1];
  const float* bqkv = (const float*)d_in[2];
  const float* wout = (const float*)d_in[3];
  const float* bout = (const float*)d_in[4];
  const float* w1   = (const float*)d_in[5];
  const float* b1   = (const float*)d_in[6];
  const float* w2   = (const float*)d_in[7];
  const float* b2   = (const float*)d_in[8];
  float* out = (float*)d_out;
  char* wsb = (char*)d_ws;
  const size_t MB = 1048576;

  // ws: xf 16@0 | wqf 8@16 | wcat 8@24 | qkvF 48@32 | VtF 16@80 | cat 32@96
  //   | cholT 16@128 | tab (ftab 2048 + twtab 1024 float2) @145
  f16*   xf    = (f16*)(wsb);
  f16*   wqf   = (f16*)(wsb + 16 * MB);
  f16*   wcat  = (f16*)(wsb + 24 * MB);
  f16*   qkvF  = (f16*)(wsb + 32 * MB);
  f16*   VtF   = (f16*)(wsb + 80 * MB);
  f16*   cat   = (f16*)(wsb + 96 * MB);
  f16*   cholT = (f16*)(wsb + 128 * MB);
  float2* tab  = (float2*)(wsb + 145 * MB);

  conv_all<<<7184, 256, 0, stream>>>(x, wqkv, w1, wout, w2, xf, tab);

  // GEMM A: [qkv | gelu(h)] = xf @ [Wqkv;W1]^T; V written transposed to VtF
  gemm_f16<3><<<dim3(32, 64), 256, 0, stream>>>(xf, wqf, bqkv, b1, qkvF, cat, VtF, 4096, 1024);
  flash_f16<<<256, 512, 0, stream>>>(qkvF, VtF, cat);   // writes cat low half
  // GEMM B: cholT = ([attn|h] @ [1.8Wout|0.2W2]^T + 1.8bout + 0.2b2)^T
  gemm_f16<4><<<dim3(8, 64), 256, 0, stream>>>(cat, wcat, bout, b2, cholT, nullptr, nullptr, 1024, 2048);
  spectral7<<<1024, 256, 0, stream>>>(cholT, x, tab, out);
}